// Round 4
// baseline (128.093 us; speedup 1.0000x reference)
//
#include <hip/hip_runtime.h>
#include <math.h>

// HebbianMemory: x(8,2048,512) f32; k/v/q = x@W+b; scan:
//   mem_t = q_t @ state ; state = 0.9*state + 0.1*outer(k_t, v_t)
// out = mems@Wo+bo ; outputs: out (8,2048,512) then final_state (8,512,512).
//
// Banded-attention formulation (decay truncation lam^128=1.4e-6):
//   mem_j = [lam128 Qh Kh^T_{j-2} | lam64 Qh Kh^T_{j-1} | strictlow(Qh Kh^T_j)]
//           @ [V_{j-2}; V_{j-1}; V_j]            -- fully parallel over j
//   final_state = lam64 (G31 + lam64 (G30 + lam64 G29)),  G_j = Kh_j^T V_j
// GEMMs: round-15 structure (BK=32 dbuf, 128x128, packed-line swizzle) +
// T4 counted vmcnt. khT trim (R3): z=1 transposed epilogue only on tl>=1792.
// R4: prep x->bf16 pass removed; proj (EMODE 0) stages f32 x directly via
// global_load_lds (A tile [128][32] f32, 128B/row lines, same XOR swizzle)
// and converts to bf16 at fragment read (f2bf == RNE, numerics unchanged).
// Saves ~8us of HBM round-trip; out-GEMM (EMODE 1) keeps bf16 A path.

#define DIMD 512
#define SEQL 2048
#define LRC 0.1f
#define LAM64 1.1790184577738602e-3f    // 0.9^64
#define LAM128 1.3900845237714473e-6f   // 0.9^128
#define L2LAM -0.15200309344504997f     // log2(0.9)

#define KVQ_ELEMS ((size_t)16384 * 512)   // 8388608
#define WSLAB ((size_t)512 * 512)

typedef __attribute__((ext_vector_type(8))) short bf16x8;
typedef __attribute__((ext_vector_type(4))) float f32x4;

__device__ __forceinline__ unsigned short f2bf(float f) {
  unsigned int u = __float_as_uint(f);
  u += 0x7FFFu + ((u >> 16) & 1u);
  return (unsigned short)(u >> 16);
}

// async global->LDS, 16B per lane; lds base must be wave-uniform
__device__ __forceinline__ void gload16(const void* g, char* l) {
  __builtin_amdgcn_global_load_lds(
      (const __attribute__((address_space(1))) unsigned int*)g,
      (__attribute__((address_space(3))) unsigned int*)l, 16, 0, 0);
}

// ---------------- prepw: W -> W^T bf16 (1024 blocks) ----------------
__global__ __launch_bounds__(256) void prepw(
    const float* __restrict__ Wq, const float* __restrict__ Wk,
    const float* __restrict__ Wv, const float* __restrict__ Wo,
    unsigned short* __restrict__ T) {
  const int r2 = blockIdx.x;     // 0..1023
  const int z = r2 >> 8;         // 0..3
  const int rem = r2 & 255;
  const int nb = (rem & 15) * 32, kb = (rem >> 4) * 32;
  const float* W = (z == 0) ? Wq : (z == 1) ? Wk : (z == 2) ? Wv : Wo;
  unsigned short* Tz = T + (size_t)z * WSLAB;
  __shared__ float tl[32][33];
  const int r = threadIdx.x >> 5, c = threadIdx.x & 31;
#pragma unroll
  for (int i = 0; i < 4; ++i)
    tl[r + i * 8][c] = W[(size_t)(kb + r + i * 8) * 512 + nb + c];
  __syncthreads();
#pragma unroll
  for (int i = 0; i < 4; ++i)
    Tz[(size_t)(nb + r + i * 8) * 512 + kb + c] = f2bf(tl[c][r + i * 8]);
}

// ---------------- bf16 MFMA GEMM (128x128 tile, BK=32, 4 waves) ----------------
// Double-buffered, ISSUE-ahead, counted vmcnt (T4).
// EMODE 0: A is f32 (x direct). LDS: A[2][16K] at 0 ([128][32]f32, 128B rows,
//   off ^ ((row&7)<<4), inverse on gload source), B[2][8K] at 32K (packed-line
//   bf16, as before). 6 loads/lane/tile -> vmcnt(6). Fragment read converts
//   f32->bf16 in-reg. Epilogue: z=0 q_hat; z=1 k_hat (+k_hatT tl>=1792); z=2 vT.
// EMODE 1: A bf16 (mbf). LDS: A[2][8K] at 0, B[2][8K] at 16K; vmcnt(4).
//   Epilogue: f32 C+bias.
template <int EMODE>
__global__ __launch_bounds__(256) void mfma_gemm(
    const void* __restrict__ A, int astr,
    const unsigned short* __restrict__ T0, const unsigned short* __restrict__ T1,
    const unsigned short* __restrict__ T2, int tstr,
    const float* __restrict__ b0, const float* __restrict__ b1,
    const float* __restrict__ b2,
    float* __restrict__ Cf,
    unsigned short* __restrict__ qh, unsigned short* __restrict__ kh,
    unsigned short* __restrict__ khT, unsigned short* __restrict__ vTp,
    int nkt) {
  const int z = blockIdx.z;
  const unsigned short* T = (z == 0) ? T0 : (z == 1) ? T1 : T2;
  const float* bias = (z == 0) ? b0 : (z == 1) ? b1 : b2;

  const int m0 = blockIdx.x * 128;
  const int n0 = blockIdx.y * 128;
  const int tid = threadIdx.x;
  const int lane = tid & 63;
  const int w = tid >> 6;
  const int wm = (w & 1) * 64;
  const int wn = (w >> 1) * 64;

  constexpr int ABUF = (EMODE == 0) ? 16384 : 8192;  // per A buffer
  constexpr int BB0 = 2 * ABUF;                      // B region base
  // EMODE0: K-loop 48K; epilogue cl[128][136] (34816) fits. EMODE1: 32K.
  __shared__ __align__(16) char smem[(EMODE == 0) ? 49152 : 32768];

  f32x4 acc[4][4];
  const f32x4 zf = {0.f, 0.f, 0.f, 0.f};
#pragma unroll
  for (int i = 0; i < 4; ++i)
#pragma unroll
    for (int j = 0; j < 4; ++j) acc[i][j] = zf;

  // ---- staging geometry ----
  // B (bf16, both modes): packed-line scheme, dest L = lane*16 in wave's 2KB
  const int lr = lane >> 3;
  const int lo3 = lane & 7;
  const int xr = lo3 ^ lr;
  const int mbase = w * 32 + lr * 2 + (xr >> 2);
  const int kel = (xr & 3) * 8;
  const unsigned short* Tg = T + (size_t)(n0 + mbase) * tstr + kel;
  // A f32 (EMODE 0): lane covers line w*32 + c*8 + (lane>>3), byte (lane&7)*16
  const float* Agf = (const float*)A +
      (size_t)(m0 + w * 32 + lr) * astr + ((lo3 ^ lr) * 4);
  // A bf16 (EMODE 1): same scheme as B
  const unsigned short* Agb = (const unsigned short*)A +
      (size_t)(m0 + mbase) * astr + kel;

#define ISSUE_A0(KT, BUF)                                                  \
  { char* d = smem + (BUF) * 16384 + w * 4096;                             \
    _Pragma("unroll") for (int c = 0; c < 4; ++c)                          \
      gload16(Agf + (size_t)(c * 8) * astr + (KT) * 32, d + c * 1024); }
#define ISSUE_A1(KT, BUF)                                                  \
  { char* d = smem + (BUF) * 8192 + w * 2048;                              \
    _Pragma("unroll") for (int c = 0; c < 2; ++c)                          \
      gload16(Agb + (size_t)(c * 16) * astr + (KT) * 32, d + c * 1024); }
#define ISSUE_B(KT, BUF)                                                   \
  { char* d = smem + BB0 + (BUF) * 8192 + w * 2048;                        \
    _Pragma("unroll") for (int c = 0; c < 2; ++c)                          \
      gload16(Tg + (size_t)(c * 16) * tstr + (KT) * 32, d + c * 1024); }
#define ISSUE(KT, BUF)                                                     \
  { if constexpr (EMODE == 0) { ISSUE_A0(KT, BUF); } else { ISSUE_A1(KT, BUF); } \
    ISSUE_B(KT, BUF); }

  // ---- fragment-read geometry ----
  const int fr = lane & 15;
  const int fg = lane >> 4;
  // bf16 packed-line (B always; A in EMODE 1):
  const int foff = ((((fr & 1) << 6) | (fg << 4)) ^ (((fr >> 1) & 7) << 4));
  const int aline = (wm >> 1) + (fr >> 1);
  const int bline = (wn >> 1) + (fr >> 1);
  // f32 A (EMODE 0): row = wm + mi*16 + fr, bytes fg*32..+32, swz (fr&7)<<4
  const int xswA = (fr & 7) << 4;
  const int offA0 = (fg * 32) ^ xswA;
  const int offA1 = (fg * 32 + 16) ^ xswA;

  ISSUE(0, 0);
  int bb = 0;
  for (int kt = 0; kt < nkt; ++kt) {
    if (kt + 1 < nkt) {
      ISSUE(kt + 1, bb ^ 1);  // next tile in flight
      if constexpr (EMODE == 0)
        asm volatile("s_waitcnt vmcnt(6)" ::: "memory");  // tile kt resident
      else
        asm volatile("s_waitcnt vmcnt(4)" ::: "memory");
    } else {
      asm volatile("s_waitcnt vmcnt(0)" ::: "memory");
    }
    __builtin_amdgcn_sched_barrier(0);
    __builtin_amdgcn_s_barrier();   // all waves' tile-kt loads landed
    bf16x8 af[4], bfr[4];
    if constexpr (EMODE == 0) {
      const char* pa = smem + bb * 16384 + (wm + fr) * 128;
#pragma unroll
      for (int mi = 0; mi < 4; ++mi) {
        f32x4 lo = *(const f32x4*)(pa + mi * 2048 + offA0);
        f32x4 hi = *(const f32x4*)(pa + mi * 2048 + offA1);
#pragma unroll
        for (int e = 0; e < 4; ++e) {
          af[mi][e] = (short)f2bf(lo[e]);
          af[mi][e + 4] = (short)f2bf(hi[e]);
        }
      }
    } else {
      const char* pa = smem + bb * 8192 + aline * 128 + foff;
#pragma unroll
      for (int mi = 0; mi < 4; ++mi) af[mi] = *(const bf16x8*)(pa + mi * 1024);
    }
    const char* pb = smem + BB0 + bb * 8192 + bline * 128 + foff;
#pragma unroll
    for (int ni = 0; ni < 4; ++ni) bfr[ni] = *(const bf16x8*)(pb + ni * 1024);
#pragma unroll
    for (int mi = 0; mi < 4; ++mi)
#pragma unroll
      for (int ni = 0; ni < 4; ++ni)
        acc[mi][ni] = __builtin_amdgcn_mfma_f32_16x16x32_bf16(
            af[mi], bfr[ni], acc[mi][ni], 0, 0, 0);
    __builtin_amdgcn_s_barrier();   // all reads of buf bb done
    __builtin_amdgcn_sched_barrier(0);
    bb ^= 1;
  }
#undef ISSUE
#undef ISSUE_A0
#undef ISSUE_A1
#undef ISSUE_B

  const int orow = fg * 4;

  if (EMODE == 1) {
#pragma unroll
    for (int ni = 0; ni < 4; ++ni) {
      const int col = n0 + wn + ni * 16 + fr;
      const float bi = bias[col];
#pragma unroll
      for (int mi = 0; mi < 4; ++mi) {
        float* cp = Cf + (size_t)(m0 + wm + mi * 16 + orow) * 512 + col;
#pragma unroll
        for (int r = 0; r < 4; ++r) cp[(size_t)r * 512] = acc[mi][ni][r] + bi;
      }
    }
    return;
  }

  __syncthreads();  // full drain; smem reusable
  unsigned short* cl = (unsigned short*)smem;  // [128][136]
  const size_t batch = (size_t)(m0 >> 11);
  const int tl = m0 & 2047;

  if (z <= 1) {
    // pass A: row-major [row][col]
#pragma unroll
    for (int ni = 0; ni < 4; ++ni) {
      const int col = wn + ni * 16 + fr;
      const float bi = bias[n0 + col];
#pragma unroll
      for (int mi = 0; mi < 4; ++mi) {
#pragma unroll
        for (int r = 0; r < 4; ++r) {
          const int row = wm + mi * 16 + orow + r;
          float v = acc[mi][ni][r] + bi;
          v *= (z == 0) ? exp2f(L2LAM * (float)(row & 63))
                        : LRC * exp2f(-L2LAM * (float)((row & 63) + 1));
          cl[row * 136 + col] = f2bf(v);
        }
      }
    }
    __syncthreads();
    {
      const int row = tid >> 1, half = tid & 1;
      unsigned short* dst = (z == 0 ? qh : kh) +
          (size_t)(m0 + row) * DIMD + n0 + half * 64;
      const unsigned short* sp = cl + row * 136 + half * 64;
#pragma unroll
      for (int j = 0; j < 8; ++j)
        *(float4*)(dst + j * 8) = *(const float4*)(sp + j * 8);
    }
  }
  // transposed pass: vT always; khT only where fstate reads (t >= 1856)
  if (z == 2 || (z == 1 && tl >= 1792)) {
    __syncthreads();  // pass A reads done before overwrite
    // pass B: col-major [col][row]
#pragma unroll
    for (int ni = 0; ni < 4; ++ni) {
      const int col = wn + ni * 16 + fr;
      const float bi = bias[n0 + col];
#pragma unroll
      for (int mi = 0; mi < 4; ++mi) {
#pragma unroll
        for (int r = 0; r < 4; ++r) {
          const int row = wm + mi * 16 + orow + r;
          float v = acc[mi][ni][r] + bi;
          if (z == 1) v *= LRC * exp2f(-L2LAM * (float)((row & 63) + 1));
          cl[col * 136 + row] = f2bf(v);
        }
      }
    }
    __syncthreads();
    {
      const int col = tid >> 1, half = tid & 1;
      unsigned short* dstT = (z == 1 ? khT : vTp) + batch * DIMD * SEQL +
          (size_t)(n0 + col) * SEQL + tl + half * 64;
      const unsigned short* sp = cl + col * 136 + half * 64;
#pragma unroll
      for (int j = 0; j < 8; ++j)
        *(float4*)(dstT + j * 8) = *(const float4*)(sp + j * 8);
    }
  }
}

// ---------------- banded attention + fused final-state ----------------
// blocks 0..511: battn (2 e-halves x 32 t-blocks x 8 batches), 4 waves.
// blocks 512..639: final_state = lam64(G31 + lam64(G30 + lam64 G29)).
__global__ __launch_bounds__(256) void battn(
    const unsigned short* __restrict__ qh, const unsigned short* __restrict__ kh,
    const unsigned short* __restrict__ vTp, const unsigned short* __restrict__ khT,
    unsigned short* __restrict__ mbf, float* __restrict__ fstate) {
  const int blk = blockIdx.x;
  const int tid = threadIdx.x;
  const int lane = tid & 63;
  const int w = tid >> 6;
  const int fr = lane & 15;
  const int fg = lane >> 4;

  __shared__ __align__(16) char Kl[65536];              // K_sb [64][1024B] swz
  __shared__ __align__(16) unsigned short Pl[64 * 72];  // P [t][s], stride 72

  if (blk >= 512) {
    // ---- fstatek path ----
    const int b2 = blk - 512;
    const int b = b2 & 7;
    const int slab = b2 >> 3;  // 0..15
    const int e0g = slab * 32;
    const int wd0 = w * 128;
    const unsigned short* kTb = khT + (size_t)b * DIMD * SEQL;
    const unsigned short* vTb = vTp + (size_t)b * DIMD * SEQL;

    f32x4 S[8][2];
    const f32x4 zf = {0.f, 0.f, 0.f, 0.f};
#pragma unroll
    for (int mi = 0; mi < 8; ++mi)
#pragma unroll
      for (int ni = 0; ni < 2; ++ni) S[mi][ni] = zf;

#pragma unroll
    for (int tb = 29; tb < 32; ++tb) {
      const int t0 = tb * 64;
#pragma unroll
      for (int ks2 = 0; ks2 < 2; ++ks2) {
        bf16x8 aK[8], bV[2];
#pragma unroll
        for (int mi = 0; mi < 8; ++mi)
          aK[mi] = *(const bf16x8*)(kTb + (size_t)(wd0 + mi * 16 + fr) * SEQL +
                                    t0 + ks2 * 32 + fg * 8);
#pragma unroll
        for (int ni = 0; ni < 2; ++ni)
          bV[ni] = *(const bf16x8*)(vTb + (size_t)(e0g + ni * 16 + fr) * SEQL +
                                    t0 + ks2 * 32 + fg * 8);
#pragma unroll
        for (int mi = 0; mi < 8; ++mi)
#pragma unroll
          for (int ni = 0; ni < 2; ++ni)
            S[mi][ni] = __builtin_amdgcn_mfma_f32_16x16x32_bf16(aK[mi], bV[ni],
                                                                S[mi][ni], 0, 0, 0);
      }
#pragma unroll
      for (int mi = 0; mi < 8; ++mi)
#pragma unroll
        for (int ni = 0; ni < 2; ++ni) {
          S[mi][ni][0] *= LAM64;
          S[mi][ni][1] *= LAM64;
          S[mi][ni][2] *= LAM64;
          S[mi][ni][3] *= LAM64;
        }
    }
    float* fs = fstate + (size_t)b * DIMD * DIMD;
#pragma unroll
    for (int mi = 0; mi < 8; ++mi)
#pragma unroll
      for (int ni = 0; ni < 2; ++ni) {
        const int e = e0g + ni * 16 + fr;
#pragma unroll
        for (int r = 0; r < 4; ++r) {
          const int d = w * 128 + mi * 16 + fg * 4 + r;
          fs[(size_t)d * DIMD + e] = S[mi][ni][r];
        }
      }
    return;
  }

  // ---- battn path ----
  const int b = blk & 7;
  const int rest = blk >> 3;
  const int j = rest & 31;
  const int h = rest >> 5;
  const int t0 = j * 64;
  const int e0g = h * 256;
  const int wt0 = w * 16;
  const int nstartb = (j >= 2) ? 0 : (2 - j);  // first valid s-block (of 3)

  const unsigned short* qb = qh + (size_t)b * SEQL * DIMD;
  const unsigned short* kb = kh + (size_t)b * SEQL * DIMD;
  const unsigned short* vTb = vTp + (size_t)b * DIMD * SEQL;
  unsigned short* mb = mbf + (size_t)b * SEQL * DIMD;

  const int selem = lane * 8;  // 16B seg per lane, in elems

#define STAGE(S0)                                                            \
  {                                                                          \
    _Pragma("unroll") for (int c = 0; c < 16; ++c) {                         \
      const int row = w * 16 + c;                                            \
      gload16(kb + (size_t)((S0) + row) * DIMD + (selem ^ ((row & 7) << 3)), \
              Kl + row * 1024);                                              \
    }                                                                        \
  }

  // prologue: stage first s-block
  STAGE(t0 - 128 + nstartb * 64);

  // hoist Q fragments (per-wave-own t-rows, reused across s-blocks)
  bf16x8 aq[16];
  {
    const unsigned short* qrow = qb + (size_t)(t0 + wt0 + fr) * DIMD + fg * 8;
#pragma unroll
    for (int ks = 0; ks < 16; ++ks) aq[ks] = *(const bf16x8*)(qrow + ks * 32);
  }

  f32x4 mem[4][4];
  const f32x4 zf = {0.f, 0.f, 0.f, 0.f};
#pragma unroll
  for (int mi = 0; mi < 4; ++mi)
#pragma unroll
    for (int ni = 0; ni < 4; ++ni) mem[mi][ni] = zf;

  const int ew = e0g + w * 64;  // this wave's e-stripe for PV

  for (int sb = nstartb; sb < 3; ++sb) {
    const int s0 = t0 - 128 + sb * 64;
    __syncthreads();  // K(sb) resident (vmcnt drained); Pl free

    // ---- P = Qh @ K_sb^T (K from LDS) ----
    f32x4 P[4];
#pragma unroll
    for (int ni = 0; ni < 4; ++ni) P[ni] = zf;
#pragma unroll
    for (int ks = 0; ks < 16; ++ks) {
      bf16x8 bK[4];
#pragma unroll
      for (int ni = 0; ni < 4; ++ni) {
        const int row = ni * 16 + fr;
        bK[ni] = *(const bf16x8*)(Kl + row * 1024 +
                                  ((ks * 64 + fg * 16) ^ ((row & 7) << 4)));
      }
#pragma unroll
      for (int ni = 0; ni < 4; ++ni)
        P[ni] = __builtin_amdgcn_mfma_f32_16x16x32_bf16(aq[ks], bK[ni], P[ni], 0, 0, 0);
    }

    // ---- weight + write P to LDS (own t-rows) ----
#pragma unroll
    for (int ni = 0; ni < 4; ++ni) {
      const int s = ni * 16 + fr;
#pragma unroll
      for (int r = 0; r < 4; ++r) {
        const int t = wt0 + fg * 4 + r;
        float v = (sb == 0) ? P[ni][r] * LAM128
                : (sb == 1) ? P[ni][r] * LAM64
                            : ((s < t) ? P[ni][r] : 0.f);
        Pl[t * 72 + s] = f2bf(v);
      }
    }
    __syncthreads();  // P ready; all Kl reads done
    if (sb + 1 < 3) STAGE(s0 + 64);  // async stage overlaps PV

    // ---- mem += P @ V_sb : all 64 t-rows x own 64 e-cols ----
#pragma unroll
    for (int ks2 = 0; ks2 < 2; ++ks2) {
      bf16x8 ap[4];
#pragma unroll
      for (int mi = 0; mi < 4; ++mi)
        ap[mi] = *(const bf16x8*)(Pl + (mi * 16 + fr) * 72 + ks2 * 32 + fg * 8);
      const int tk = s0 + ks2 * 32 + fg * 8;
#pragma unroll
      for (int ni = 0; ni < 4; ++ni) {
        bf16x8 bV = *(const bf16x8*)(vTb + (size_t)(ew + ni * 16 + fr) * SEQL + tk);
#pragma unroll
        for (int mi = 0; mi < 4; ++mi)
          mem[mi][ni] = __builtin_amdgcn_mfma_f32_16x16x32_bf16(ap[mi], bV,
                                                               mem[mi][ni], 0, 0, 0);
      }
    }
  }
#undef STAGE

  // store mems bf16: all 64 t x own e-stripe
#pragma unroll
  for (int mi = 0; mi < 4; ++mi)
#pragma unroll
    for (int ni = 0; ni < 4; ++ni)
#pragma unroll
      for (int r = 0; r < 4; ++r) {
        const int t = t0 + mi * 16 + fg * 4 + r;
        mb[(size_t)t * DIMD + ew + ni * 16 + fr] = f2bf(mem[mi][ni][r]);
      }
}

extern "C" void kernel_launch(void* const* d_in, const int* in_sizes, int n_in,
                              void* d_out, int out_size, void* d_ws,
                              size_t ws_size, hipStream_t stream) {
  const float* x  = (const float*)d_in[0];
  const float* Wk = (const float*)d_in[1];
  const float* bk = (const float*)d_in[2];
  const float* Wv = (const float*)d_in[3];
  const float* bv = (const float*)d_in[4];
  const float* Wq = (const float*)d_in[5];
  const float* bq = (const float*)d_in[6];
  const float* Wo = (const float*)d_in[7];
  const float* bo = (const float*)d_in[8];

  float* outp = (float*)d_out;
  float* fstate = outp + KVQ_ELEMS;

  // ws layout (~86 MB < 100.7 proven):
  unsigned short* qhb = (unsigned short*)d_ws;          // q_hat [b][t][d]
  unsigned short* khb = qhb + KVQ_ELEMS;                // k_hat [b][t][d]
  unsigned short* khT = qhb + 2 * KVQ_ELEMS;            // k_hat^T [b][d][t] (t>=1792 only)
  unsigned short* vTp = qhb + 3 * KVQ_ELEMS;            // v^T [b][e][t]
  unsigned short* mbf = qhb + 4 * KVQ_ELEMS;            // mems bf16 [b][t][e]
  unsigned short* WT  = qhb + 5 * KVQ_ELEMS;            // W^T bf16 x4

  // 1) W -> W^T bf16 only (x is consumed f32 directly by proj)
  prepw<<<dim3(1024), 256, 0, stream>>>(Wq, Wk, Wv, Wo, WT);
  // 2) projections (K=512, BK=32 -> nkt=16) -> q_hat, k_hat(+T trimmed), v^T bf16
  mfma_gemm<0><<<dim3(128, 4, 3), 256, 0, stream>>>(
      x, 512, WT /*Wq*/, WT + WSLAB /*Wk*/, WT + 2 * WSLAB /*Wv*/, 512,
      bq, bk, bv, nullptr, qhb, khb, khT, vTp, 16);
  // 3) banded attention -> mems bf16 (blocks 0..511) + final_state (512..639)
  battn<<<dim3(640), 256, 0, stream>>>(qhb, khb, vTp, khT, mbf, fstate);
  // 4) out = mems @ Wo + bo (K=512, nkt=16)
  mfma_gemm<1><<<dim3(128, 4, 1), 256, 0, stream>>>(
      mbf, 512, WT + 3 * WSLAB, WT + 3 * WSLAB, WT + 3 * WSLAB, 512,
      bo, bo, bo, outp, nullptr, nullptr, nullptr, nullptr, 16);
}

// Round 5
// 110.496 us; speedup vs baseline: 1.1593x; 1.1593x over previous
//
#include <hip/hip_runtime.h>
#include <math.h>

// HebbianMemory: x(8,2048,512) f32; k/v/q = x@W+b; scan:
//   mem_t = q_t @ state ; state = 0.9*state + 0.1*outer(k_t, v_t)
// out = mems@Wo+bo ; outputs: out (8,2048,512) then final_state (8,512,512).
//
// Banded-attention formulation (decay truncation lam^128=1.4e-6):
//   mem_j = [lam128 Qh Kh^T_{j-2} | lam64 Qh Kh^T_{j-1} | strictlow(Qh Kh^T_j)]
//           @ [V_{j-2}; V_{j-1}; V_j]            -- fully parallel over j
//   final_state = lam64 (G31 + lam64 (G30 + lam64 G29)),  G_j = Kh_j^T V_j
// GEMMs: round-15 structure (BK=32 dbuf, 128x128, packed-line swizzle) +
// T4 counted vmcnt. khT trim (R3): z=1 transposed epilogue only on tl>=1792.
// R4 (f32-direct A staging) REVERTED: 3.4M bank conflicts + 40% VALU + 72MB
// fetch; bf16 prep round-trip is cheaper. R5: battn e-halves merged -- old
// blocks (b,j,h=0/1) computed identical P=QK^T; now one 512-thread block
// (8 waves: QK^T split by (t-group, s-half), PV by 64-wide e-stripe) does
// it once. Halves QK^T MFMA + K staging; outputs bit-identical.

#define DIMD 512
#define SEQL 2048
#define LRC 0.1f
#define LAM64 1.1790184577738602e-3f    // 0.9^64
#define LAM128 1.3900845237714473e-6f   // 0.9^128
#define L2LAM -0.15200309344504997f     // log2(0.9)

#define KVQ_ELEMS ((size_t)16384 * 512)   // 8388608
#define WSLAB ((size_t)512 * 512)

typedef __attribute__((ext_vector_type(8))) short bf16x8;
typedef __attribute__((ext_vector_type(4))) float f32x4;

__device__ __forceinline__ unsigned short f2bf(float f) {
  unsigned int u = __float_as_uint(f);
  u += 0x7FFFu + ((u >> 16) & 1u);
  return (unsigned short)(u >> 16);
}

// async global->LDS, 16B per lane; lds base must be wave-uniform
__device__ __forceinline__ void gload16(const unsigned short* g, char* l) {
  __builtin_amdgcn_global_load_lds(
      (const __attribute__((address_space(1))) unsigned int*)g,
      (__attribute__((address_space(3))) unsigned int*)l, 16, 0, 0);
}

// ---------------- prep: x->bf16 (blocks 0..8191) + W->W^T bf16 (8192..9215) --
__global__ __launch_bounds__(256) void prep(
    const float* __restrict__ x, unsigned short* __restrict__ Abf,
    const float* __restrict__ Wq, const float* __restrict__ Wk,
    const float* __restrict__ Wv, const float* __restrict__ Wo,
    unsigned short* __restrict__ T) {
  const int blk = blockIdx.x;
  if (blk < 8192) {
    const size_t idx = ((size_t)blk * 256 + threadIdx.x) * 4;
    float4 v = *(const float4*)(x + idx);
    ushort4 u;
    u.x = f2bf(v.x); u.y = f2bf(v.y); u.z = f2bf(v.z); u.w = f2bf(v.w);
    *(ushort4*)(Abf + idx) = u;
    return;
  }
  const int r2 = blk - 8192;     // 0..1023
  const int z = r2 >> 8;         // 0..3
  const int rem = r2 & 255;
  const int nb = (rem & 15) * 32, kb = (rem >> 4) * 32;
  const float* W = (z == 0) ? Wq : (z == 1) ? Wk : (z == 2) ? Wv : Wo;
  unsigned short* Tz = T + (size_t)z * WSLAB;
  __shared__ float tl[32][33];
  const int r = threadIdx.x >> 5, c = threadIdx.x & 31;
#pragma unroll
  for (int i = 0; i < 4; ++i)
    tl[r + i * 8][c] = W[(size_t)(kb + r + i * 8) * 512 + nb + c];
  __syncthreads();
#pragma unroll
  for (int i = 0; i < 4; ++i)
    Tz[(size_t)(nb + r + i * 8) * 512 + kb + c] = f2bf(tl[c][r + i * 8]);
}

// ---------------- bf16 MFMA GEMM (128x128 tile, BK=32, 4 waves) ----------------
// Double-buffered, ISSUE-ahead, counted vmcnt (T4). LDS: A[2][8K] at 0,
// B[2][8K] at 16K. Line = 2 packed rows (128B); read off ^ ((line&7)<<4),
// inverse on gload source.
// EMODE 0 epilogue: z=0 q_hat; z=1 k_hat (+k_hatT on tl>=1792); z=2 vT.
// EMODE 1: f32 C+bias.
template <int EMODE>
__global__ __launch_bounds__(256) void mfma_gemm(
    const unsigned short* __restrict__ A, int astr,
    const unsigned short* __restrict__ T0, const unsigned short* __restrict__ T1,
    const unsigned short* __restrict__ T2, int tstr,
    const float* __restrict__ b0, const float* __restrict__ b1,
    const float* __restrict__ b2,
    float* __restrict__ Cf,
    unsigned short* __restrict__ qh, unsigned short* __restrict__ kh,
    unsigned short* __restrict__ khT, unsigned short* __restrict__ vTp,
    int nkt) {
  const int z = blockIdx.z;
  const unsigned short* T = (z == 0) ? T0 : (z == 1) ? T1 : T2;
  const float* bias = (z == 0) ? b0 : (z == 1) ? b1 : b2;

  const int m0 = blockIdx.x * 128;
  const int n0 = blockIdx.y * 128;
  const int tid = threadIdx.x;
  const int lane = tid & 63;
  const int w = tid >> 6;
  const int wm = (w & 1) * 64;
  const int wn = (w >> 1) * 64;

  // dbuf 32KB; EMODE 0 epilogue reuses as cl[128][136] bf16 (34816B)
  __shared__ __align__(16) char smem[EMODE == 0 ? 35840 : 32768];

  f32x4 acc[4][4];
  const f32x4 zf = {0.f, 0.f, 0.f, 0.f};
#pragma unroll
  for (int i = 0; i < 4; ++i)
#pragma unroll
    for (int j = 0; j < 4; ++j) acc[i][j] = zf;

  // ---- staging geometry (per lane): dest L = lane*16 within wave's 2KB ----
  const int lr = lane >> 3;
  const int lo3 = lane & 7;
  const int xr = lo3 ^ lr;
  const int mbase = w * 32 + lr * 2 + (xr >> 2);
  const int kel = (xr & 3) * 8;
  const unsigned short* Ag = A + (size_t)(m0 + mbase) * astr + kel;
  const unsigned short* Tg = T + (size_t)(n0 + mbase) * tstr + kel;

#define ISSUE(KT, BUF)                                                     \
  {                                                                        \
    char* ab = smem + (BUF) * 8192 + w * 2048;                             \
    char* bb_ = smem + 16384 + (BUF) * 8192 + w * 2048;                    \
    _Pragma("unroll") for (int c = 0; c < 2; ++c) {                        \
      gload16(Ag + (size_t)(c * 16) * astr + (KT) * 32, ab + c * 1024);    \
      gload16(Tg + (size_t)(c * 16) * tstr + (KT) * 32, bb_ + c * 1024);   \
    }                                                                      \
  }

  // ---- fragment-read geometry ----
  const int fr = lane & 15;
  const int fg = lane >> 4;
  const int foff = ((((fr & 1) << 6) | (fg << 4)) ^ (((fr >> 1) & 7) << 4));
  const int aline = (wm >> 1) + (fr >> 1);
  const int bline = (wn >> 1) + (fr >> 1);

  ISSUE(0, 0);
  int bb = 0;
  for (int kt = 0; kt < nkt; ++kt) {
    if (kt + 1 < nkt) {
      ISSUE(kt + 1, bb ^ 1);  // 4 more in flight (8 total)
      asm volatile("s_waitcnt vmcnt(4)" ::: "memory");  // tile kt resident
    } else {
      asm volatile("s_waitcnt vmcnt(0)" ::: "memory");
    }
    __builtin_amdgcn_sched_barrier(0);
    __builtin_amdgcn_s_barrier();   // all waves' tile-kt loads landed
    const char* pa = smem + bb * 8192 + aline * 128 + foff;
    const char* pb = smem + 16384 + bb * 8192 + bline * 128 + foff;
    bf16x8 af[4], bfr[4];
#pragma unroll
    for (int mi = 0; mi < 4; ++mi) af[mi] = *(const bf16x8*)(pa + mi * 1024);
#pragma unroll
    for (int ni = 0; ni < 4; ++ni) bfr[ni] = *(const bf16x8*)(pb + ni * 1024);
#pragma unroll
    for (int mi = 0; mi < 4; ++mi)
#pragma unroll
      for (int ni = 0; ni < 4; ++ni)
        acc[mi][ni] = __builtin_amdgcn_mfma_f32_16x16x32_bf16(
            af[mi], bfr[ni], acc[mi][ni], 0, 0, 0);
    __builtin_amdgcn_s_barrier();   // all reads of buf bb done (lgkm drained by MFMA deps)
    __builtin_amdgcn_sched_barrier(0);
    bb ^= 1;
  }
#undef ISSUE

  const int orow = fg * 4;

  if (EMODE == 1) {
#pragma unroll
    for (int ni = 0; ni < 4; ++ni) {
      const int col = n0 + wn + ni * 16 + fr;
      const float bi = bias[col];
#pragma unroll
      for (int mi = 0; mi < 4; ++mi) {
        float* cp = Cf + (size_t)(m0 + wm + mi * 16 + orow) * 512 + col;
#pragma unroll
        for (int r = 0; r < 4; ++r) cp[(size_t)r * 512] = acc[mi][ni][r] + bi;
      }
    }
    return;
  }

  __syncthreads();  // full drain; smem reusable
  unsigned short* cl = (unsigned short*)smem;  // [128][136]
  const size_t batch = (size_t)(m0 >> 11);
  const int tl = m0 & 2047;

  if (z <= 1) {
    // pass A: row-major [row][col]
#pragma unroll
    for (int ni = 0; ni < 4; ++ni) {
      const int col = wn + ni * 16 + fr;
      const float bi = bias[n0 + col];
#pragma unroll
      for (int mi = 0; mi < 4; ++mi) {
#pragma unroll
        for (int r = 0; r < 4; ++r) {
          const int row = wm + mi * 16 + orow + r;
          float v = acc[mi][ni][r] + bi;
          v *= (z == 0) ? exp2f(L2LAM * (float)(row & 63))
                        : LRC * exp2f(-L2LAM * (float)((row & 63) + 1));
          cl[row * 136 + col] = f2bf(v);
        }
      }
    }
    __syncthreads();
    {
      const int row = tid >> 1, half = tid & 1;
      unsigned short* dst = (z == 0 ? qh : kh) +
          (size_t)(m0 + row) * DIMD + n0 + half * 64;
      const unsigned short* sp = cl + row * 136 + half * 64;
#pragma unroll
      for (int j = 0; j < 8; ++j)
        *(float4*)(dst + j * 8) = *(const float4*)(sp + j * 8);
    }
  }
  // transposed pass: vT always; khT only where fstate reads (t >= 1856)
  if (z == 2 || (z == 1 && tl >= 1792)) {
    __syncthreads();  // pass A reads done before overwrite
    // pass B: col-major [col][row]
#pragma unroll
    for (int ni = 0; ni < 4; ++ni) {
      const int col = wn + ni * 16 + fr;
      const float bi = bias[n0 + col];
#pragma unroll
      for (int mi = 0; mi < 4; ++mi) {
#pragma unroll
        for (int r = 0; r < 4; ++r) {
          const int row = wm + mi * 16 + orow + r;
          float v = acc[mi][ni][r] + bi;
          if (z == 1) v *= LRC * exp2f(-L2LAM * (float)((row & 63) + 1));
          cl[col * 136 + row] = f2bf(v);
        }
      }
    }
    __syncthreads();
    {
      const int col = tid >> 1, half = tid & 1;
      unsigned short* dstT = (z == 1 ? khT : vTp) + batch * DIMD * SEQL +
          (size_t)(n0 + col) * SEQL + tl + half * 64;
      const unsigned short* sp = cl + col * 136 + half * 64;
#pragma unroll
      for (int j = 0; j < 8; ++j)
        *(float4*)(dstT + j * 8) = *(const float4*)(sp + j * 8);
    }
  }
}

// ---------------- banded attention + fused final-state ----------------
// 512 threads (8 waves). blocks 0..127: final_state (8 waves x 64 d-rows).
// blocks 128..383: battn, one block per (b, j) covering ALL 512 e-cols:
//   QK^T: wave w -> t-group w>>1 (16 rows), s-half w&1 (32 cols), P[2].
//   PV:   wave w -> e-stripe w*64, all 64 t-rows.
// P computed once per (b,j) (was twice, once per e-half).
__global__ __launch_bounds__(512) void battn(
    const unsigned short* __restrict__ qh, const unsigned short* __restrict__ kh,
    const unsigned short* __restrict__ vTp, const unsigned short* __restrict__ khT,
    unsigned short* __restrict__ mbf, float* __restrict__ fstate) {
  const int blk = blockIdx.x;
  const int tid = threadIdx.x;
  const int lane = tid & 63;
  const int w = tid >> 6;        // 0..7
  const int fr = lane & 15;
  const int fg = lane >> 4;

  __shared__ __align__(16) char Kl[65536];              // K_sb [64][1024B] swz
  __shared__ __align__(16) unsigned short Pl[64 * 72];  // P [t][s], stride 72

  if (blk < 128) {
    // ---- fstate path: lam64(G31 + lam64(G30 + lam64 G29)) ----
    const int b = blk & 7;
    const int slab = blk >> 3;  // 0..15
    const int e0g = slab * 32;
    const int wd0 = w * 64;
    const unsigned short* kTb = khT + (size_t)b * DIMD * SEQL;
    const unsigned short* vTb = vTp + (size_t)b * DIMD * SEQL;

    f32x4 S[4][2];
    const f32x4 zf = {0.f, 0.f, 0.f, 0.f};
#pragma unroll
    for (int mi = 0; mi < 4; ++mi)
#pragma unroll
      for (int ni = 0; ni < 2; ++ni) S[mi][ni] = zf;

#pragma unroll
    for (int tb = 29; tb < 32; ++tb) {
      const int t0 = tb * 64;
#pragma unroll
      for (int ks2 = 0; ks2 < 2; ++ks2) {
        bf16x8 aK[4], bV[2];
#pragma unroll
        for (int mi = 0; mi < 4; ++mi)
          aK[mi] = *(const bf16x8*)(kTb + (size_t)(wd0 + mi * 16 + fr) * SEQL +
                                    t0 + ks2 * 32 + fg * 8);
#pragma unroll
        for (int ni = 0; ni < 2; ++ni)
          bV[ni] = *(const bf16x8*)(vTb + (size_t)(e0g + ni * 16 + fr) * SEQL +
                                    t0 + ks2 * 32 + fg * 8);
#pragma unroll
        for (int mi = 0; mi < 4; ++mi)
#pragma unroll
          for (int ni = 0; ni < 2; ++ni)
            S[mi][ni] = __builtin_amdgcn_mfma_f32_16x16x32_bf16(aK[mi], bV[ni],
                                                                S[mi][ni], 0, 0, 0);
      }
#pragma unroll
      for (int mi = 0; mi < 4; ++mi)
#pragma unroll
        for (int ni = 0; ni < 2; ++ni) {
          S[mi][ni][0] *= LAM64;
          S[mi][ni][1] *= LAM64;
          S[mi][ni][2] *= LAM64;
          S[mi][ni][3] *= LAM64;
        }
    }
    float* fs = fstate + (size_t)b * DIMD * DIMD;
#pragma unroll
    for (int mi = 0; mi < 4; ++mi)
#pragma unroll
      for (int ni = 0; ni < 2; ++ni) {
        const int e = e0g + ni * 16 + fr;
#pragma unroll
        for (int r = 0; r < 4; ++r) {
          const int d = wd0 + mi * 16 + fg * 4 + r;
          fs[(size_t)d * DIMD + e] = S[mi][ni][r];
        }
      }
    return;
  }

  // ---- battn path ----
  const int b2 = blk - 128;
  const int b = b2 & 7;
  const int j = b2 >> 3;         // 0..31
  const int t0 = j * 64;
  const int tg = w >> 1;         // t-group 0..3 (16 rows each)
  const int sh = w & 1;          // s-half 0..1 (32 cols each)
  const int wt0 = tg * 16;
  const int nstartb = (j >= 2) ? 0 : (2 - j);  // first valid s-block (of 3)

  const unsigned short* qb = qh + (size_t)b * SEQL * DIMD;
  const unsigned short* kb = kh + (size_t)b * SEQL * DIMD;
  const unsigned short* vTb = vTp + (size_t)b * DIMD * SEQL;
  unsigned short* mb = mbf + (size_t)b * SEQL * DIMD;

  const int selem = lane * 8;  // 16B seg per lane, in elems

  // 8 waves x 8 rows = 64 rows; per (w,c): one 1024B row, lane covers 16B segs
#define STAGE(S0)                                                            \
  {                                                                          \
    _Pragma("unroll") for (int c = 0; c < 8; ++c) {                          \
      const int row = w * 8 + c;                                             \
      gload16(kb + (size_t)((S0) + row) * DIMD + (selem ^ ((row & 7) << 3)), \
              Kl + row * 1024);                                              \
    }                                                                        \
  }

  // prologue: stage first s-block
  STAGE(t0 - 128 + nstartb * 64);

  // hoist Q fragments (per-wave t-group rows, reused across s-blocks)
  bf16x8 aq[16];
  {
    const unsigned short* qrow = qb + (size_t)(t0 + wt0 + fr) * DIMD + fg * 8;
#pragma unroll
    for (int ks = 0; ks < 16; ++ks) aq[ks] = *(const bf16x8*)(qrow + ks * 32);
  }

  f32x4 mem[4][4];
  const f32x4 zf = {0.f, 0.f, 0.f, 0.f};
#pragma unroll
  for (int mi = 0; mi < 4; ++mi)
#pragma unroll
    for (int ni = 0; ni < 4; ++ni) mem[mi][ni] = zf;

  const int ew = w * 64;  // this wave's e-stripe for PV (8 x 64 = 512)

  for (int sb = nstartb; sb < 3; ++sb) {
    const int s0 = t0 - 128 + sb * 64;
    __syncthreads();  // K(sb) resident (vmcnt drained); Pl free

    // ---- P = Qh @ K_sb^T (K from LDS): own (t-group, s-half) ----
    f32x4 P[2];
#pragma unroll
    for (int nj = 0; nj < 2; ++nj) P[nj] = zf;
#pragma unroll
    for (int ks = 0; ks < 16; ++ks) {
      bf16x8 bK[2];
#pragma unroll
      for (int nj = 0; nj < 2; ++nj) {
        const int row = sh * 32 + nj * 16 + fr;
        bK[nj] = *(const bf16x8*)(Kl + row * 1024 +
                                  ((ks * 64 + fg * 16) ^ ((row & 7) << 4)));
      }
#pragma unroll
      for (int nj = 0; nj < 2; ++nj)
        P[nj] = __builtin_amdgcn_mfma_f32_16x16x32_bf16(aq[ks], bK[nj], P[nj], 0, 0, 0);
    }

    // ---- weight + write P to LDS (own t-group x s-half) ----
#pragma unroll
    for (int nj = 0; nj < 2; ++nj) {
      const int s = sh * 32 + nj * 16 + fr;
#pragma unroll
      for (int r = 0; r < 4; ++r) {
        const int t = wt0 + fg * 4 + r;
        float v = (sb == 0) ? P[nj][r] * LAM128
                : (sb == 1) ? P[nj][r] * LAM64
                            : ((s < t) ? P[nj][r] : 0.f);
        Pl[t * 72 + s] = f2bf(v);
      }
    }
    __syncthreads();  // P ready; all Kl reads done
    if (sb + 1 < 3) STAGE(s0 + 64);  // async stage overlaps PV

    // ---- mem += P @ V_sb : all 64 t-rows x own 64 e-cols ----
#pragma unroll
    for (int ks2 = 0; ks2 < 2; ++ks2) {
      bf16x8 ap[4];
#pragma unroll
      for (int mi = 0; mi < 4; ++mi)
        ap[mi] = *(const bf16x8*)(Pl + (mi * 16 + fr) * 72 + ks2 * 32 + fg * 8);
      const int tk = s0 + ks2 * 32 + fg * 8;
#pragma unroll
      for (int ni = 0; ni < 4; ++ni) {
        bf16x8 bV = *(const bf16x8*)(vTb + (size_t)(ew + ni * 16 + fr) * SEQL + tk);
#pragma unroll
        for (int mi = 0; mi < 4; ++mi)
          mem[mi][ni] = __builtin_amdgcn_mfma_f32_16x16x32_bf16(ap[mi], bV,
                                                               mem[mi][ni], 0, 0, 0);
      }
    }
  }
#undef STAGE

  // store mems bf16: all 64 t x own e-stripe
#pragma unroll
  for (int mi = 0; mi < 4; ++mi)
#pragma unroll
    for (int ni = 0; ni < 4; ++ni)
#pragma unroll
      for (int r = 0; r < 4; ++r) {
        const int t = t0 + mi * 16 + fg * 4 + r;
        mb[(size_t)t * DIMD + ew + ni * 16 + fr] = f2bf(mem[mi][ni][r]);
      }
}

extern "C" void kernel_launch(void* const* d_in, const int* in_sizes, int n_in,
                              void* d_out, int out_size, void* d_ws,
                              size_t ws_size, hipStream_t stream) {
  const float* x  = (const float*)d_in[0];
  const float* Wk = (const float*)d_in[1];
  const float* bk = (const float*)d_in[2];
  const float* Wv = (const float*)d_in[3];
  const float* bv = (const float*)d_in[4];
  const float* Wq = (const float*)d_in[5];
  const float* bq = (const float*)d_in[6];
  const float* Wo = (const float*)d_in[7];
  const float* bo = (const float*)d_in[8];

  float* outp = (float*)d_out;
  float* fstate = outp + KVQ_ELEMS;

  // ws layout (~86 MB < 100.7 proven):
  unsigned short* qhb = (unsigned short*)d_ws;          // q_hat [b][t][d]
  unsigned short* khb = qhb + KVQ_ELEMS;                // k_hat [b][t][d]
  unsigned short* khT = qhb + 2 * KVQ_ELEMS;            // k_hat^T [b][d][t] (t>=1792 only)
  unsigned short* vTp = qhb + 3 * KVQ_ELEMS;            // v^T [b][e][t]
  unsigned short* mbf = qhb + 4 * KVQ_ELEMS;            // mems bf16 [b][t][e]
  unsigned short* WT  = qhb + 5 * KVQ_ELEMS;            // W^T bf16 x4

  // pre-scan scratch inside d_out (dead until out-gemm writes it):
  unsigned short* Abf = (unsigned short*)d_out;         // x bf16 (16.8 MB)

  // 1) x -> bf16  +  W -> W^T bf16 (merged)
  prep<<<dim3(9216), 256, 0, stream>>>(x, Abf, Wq, Wk, Wv, Wo, WT);
  // 2) projections (K=512, BK=32 -> nkt=16) -> q_hat, k_hat(+T trimmed), v^T bf16
  mfma_gemm<0><<<dim3(128, 4, 3), 256, 0, stream>>>(
      Abf, 512, WT /*Wq*/, WT + WSLAB /*Wk*/, WT + 2 * WSLAB /*Wv*/, 512,
      bq, bk, bv, nullptr, qhb, khb, khT, vTp, 16);
  // 3) final_state (blocks 0..127) + banded attention (128..383), 512 thr
  battn<<<dim3(384), 512, 0, stream>>>(qhb, khb, vTp, khT, mbf, fstate);
  // 4) out = mems @ Wo + bo (K=512, nkt=16)
  mfma_gemm<1><<<dim3(128, 4, 1), 256, 0, stream>>>(
      mbf, 512, WT + 3 * WSLAB, WT + 3 * WSLAB, WT + 3 * WSLAB, 512,
      bo, bo, bo, outp, nullptr, nullptr, nullptr, nullptr, 16);
}